// Round 3
// 719.249 us; speedup vs baseline: 1.0531x; 1.0531x over previous
//
#include <hip/hip_runtime.h>
#include <cstdint>
#include <cstddef>

typedef __bf16 bf16;
typedef __attribute__((ext_vector_type(8))) bf16  bf16x8;
typedef __attribute__((ext_vector_type(4))) bf16  bf16x4;
typedef __attribute__((ext_vector_type(4))) float f32x4;

// Problem constants
#define B_SZ   2
#define T_SZ   32
#define H_SZ   18
#define W_SZ   32
#define DIM    1024
#define NHEAD  16
#define HDIM   64
#define E3     3072                  // 3*NHEAD*HDIM
#define M_TOT  36864                 // B*T*H*W
#define T_STRIDE 576                 // H_SZ*W_SZ rows per t step
#define GK     1024                  // K of both GEMMs (compile-time)
#define NKT    16                    // GK / 64

// ---------------------------------------------------------------------------
// fp32 -> bf16 conversion (vectorized x4)
// ---------------------------------------------------------------------------
__global__ void taa_cvt_bf16(const float* __restrict__ s, bf16* __restrict__ d, int n4) {
    int i = blockIdx.x * 256 + threadIdx.x;
    if (i >= n4) return;
    float4 v = ((const float4*)s)[i];
    bf16x4 o;
    o.x = (bf16)v.x; o.y = (bf16)v.y; o.z = (bf16)v.z; o.w = (bf16)v.w;
    ((bf16x4*)d)[i] = o;
}

// ---------------------------------------------------------------------------
// async global->LDS 16B (wave-uniform base + lane*16 semantics)
// ---------------------------------------------------------------------------
__device__ __forceinline__ void async_copy_16(const bf16* g, bf16* l) {
    __builtin_amdgcn_global_load_lds((__attribute__((address_space(1))) void*)g,
                                     (__attribute__((address_space(3))) void*)l,
                                     16, 0, 0);
}

#define MFMA16(a, b, c) __builtin_amdgcn_mfma_f32_16x16x32_bf16((a), (b), (c), 0, 0, 0)

// ---------------------------------------------------------------------------
// C[M,N] = A[M,K] * B[N,K]^T, bf16 in, fp32 accumulate. 256x256 tile, BK=64,
// 512 threads = 8 waves (2M x 4N), each wave 128x64 output.
// 4 phases per K-tile (8 per 2 K-tiles), raw s_barrier pairs, counted
// s_waitcnt vmcnt(8) once per K-tile (never 0 in steady state), s_setprio(1)
// around each 16-MFMA cluster.
// LDS: [2 dbuf][2 half][128][64] bf16 for A and B = 128 KiB total.
// Bank-conflict fix: 16B-chunk XOR swizzle chunk ^= (row&7), applied on the
// pre-swizzled GLOBAL source of global_load_lds (dest stays linear) and
// identically on the ds_read side (row%8 == fr%8 for every fragment row).
// Staging for K-tile kt+2 goes into the buffer being read (same parity), but
// only in phases strictly after each region's last reader passed a barrier:
//   region last reads: B halves @ phase1, A halves @ phase2
//   stage: B halves @ phase2, A halves @ phase3  -> hard-safe.
// XCD-aware bijective blockIdx swizzle (grid % 8 == 0 for both GEMMs).
// ---------------------------------------------------------------------------
template<bool OUT_BF16>
__global__ __launch_bounds__(512, 2)
void taa_gemm256(const bf16* __restrict__ A, const bf16* __restrict__ Bm,
                 void* __restrict__ Cout, const float* __restrict__ bias, int N) {
    __shared__ __align__(16) bf16 sA[2][2][8192];   // [buf][half][128*64]
    __shared__ __align__(16) bf16 sB[2][2][8192];

    const int tid  = threadIdx.x;
    const int lane = tid & 63;
    const int wv   = tid >> 6;          // 0..7
    const int wm   = wv >> 2;           // 0..1 : wave rows  wm*128
    const int wn   = wv & 3;            // 0..3 : wave cols  wn*64
    const int fr   = lane & 15;
    const int fq   = lane >> 4;

    // XCD-aware bijective swizzle (nwg % 8 == 0 guaranteed by launch)
    const int ntn = N >> 8;
    const int nwg = gridDim.x;
    const int bid = blockIdx.x;
    const int swz = (bid & 7) * (nwg >> 3) + (bid >> 3);
    const int bm  = (swz / ntn) << 8;
    const int bn  = (swz % ntn) << 8;

    // staging: per issue, thread covers LDS element range [issue*4096 + tid*8, +8)
    // of a 16KB half-buffer (linear dest). Logical row = issue*64 + tid>>3,
    // source col chunk pre-swizzled: (tid&7) ^ (row&7).
    const int srow = tid >> 3;                          // 0..63
    const int scol = ((tid & 7) ^ (srow & 7)) << 3;     // element col in [0,64)
    const bf16* gA0 = A  + (size_t)(bm + srow) * GK + scol;
    const bf16* gB0 = Bm + (size_t)(bn + srow) * GK + scol;

    // per-lane swizzled k-chunk byte offsets for fragment ds_reads
    const int swx = (fr & 7) << 4;
    const int cs0 = (fq * 16) ^ swx;          // k-step 0
    const int cs1 = (64 + fq * 16) ^ swx;     // k-step 1

    f32x4 acc[2][2][4][2];                    // [ms][ns][i][j]
#pragma unroll
    for (int ms = 0; ms < 2; ms++)
#pragma unroll
        for (int ns = 0; ns < 2; ns++)
#pragma unroll
            for (int i = 0; i < 4; i++)
#pragma unroll
                for (int j = 0; j < 2; j++)
                    acc[ms][ns][i][j] = (f32x4){0.f, 0.f, 0.f, 0.f};

    // one stage() = one 16KB half-tile = 2 global_load_lds per wave
    auto stage = [&](const bf16* g0, bf16* lbase, int h, int kt) {
        const bf16* g = g0 + (size_t)(h * 128) * GK + kt * 64;
        async_copy_16(g,                    lbase + h * 8192 + tid * 8);
        async_copy_16(g + (size_t)64 * GK,  lbase + h * 8192 + 4096 + tid * 8);
    };

    // ---- prologue: stage kt=0 -> buf0, kt=1 -> buf1 (16 issues/wave-lane) ----
    stage(gB0, &sB[0][0][0], 0, 0); stage(gB0, &sB[0][0][0], 1, 0);
    stage(gA0, &sA[0][0][0], 0, 0); stage(gA0, &sA[0][0][0], 1, 0);
    stage(gB0, &sB[1][0][0], 0, 1); stage(gB0, &sB[1][0][0], 1, 1);
    stage(gA0, &sA[1][0][0], 0, 1); stage(gA0, &sA[1][0][0], 1, 1);
    asm volatile("s_waitcnt vmcnt(8)" ::: "memory");   // kt=0 fully landed
    __builtin_amdgcn_s_barrier();
    asm volatile("" ::: "memory");

    bf16x8 af[4][2];        // A frags of current ms
    bf16x8 bfr[2][2][2];    // B frags [ns][j][s]

#pragma unroll 2
    for (int kt = 0; kt < NKT; ++kt) {
        const int buf = kt & 1;
        const char* ab = (const char*)&sA[buf][wm][0] + fr * 128;
        const char* bb = (const char*)&sB[buf][wn >> 1][0] + ((wn & 1) * 64 + fr) * 128;
        const bool st = (kt + 2 < NKT);

        // ================= phase 0: read A(ms=0)+B(ns=0); MFMA (0,0) =======
#pragma unroll
        for (int i = 0; i < 4; i++) {
            af[i][0] = *(const bf16x8*)(ab + i * 2048 + cs0);
            af[i][1] = *(const bf16x8*)(ab + i * 2048 + cs1);
        }
#pragma unroll
        for (int j = 0; j < 2; j++) {
            bfr[0][j][0] = *(const bf16x8*)(bb + j * 2048 + cs0);
            bfr[0][j][1] = *(const bf16x8*)(bb + j * 2048 + cs1);
        }
        asm volatile("" ::: "memory");
        __builtin_amdgcn_s_barrier();
        asm volatile("s_waitcnt lgkmcnt(0)" ::: "memory");
        __builtin_amdgcn_sched_barrier(0);
        __builtin_amdgcn_s_setprio(1);
#pragma unroll
        for (int i = 0; i < 4; i++)
#pragma unroll
            for (int j = 0; j < 2; j++) {
                acc[0][0][i][j] = MFMA16(af[i][0], bfr[0][j][0], acc[0][0][i][j]);
                acc[0][0][i][j] = MFMA16(af[i][1], bfr[0][j][1], acc[0][0][i][j]);
            }
        __builtin_amdgcn_s_setprio(0);
        asm volatile("" ::: "memory");
        __builtin_amdgcn_s_barrier();
        asm volatile("" ::: "memory");

        // ================= phase 1: read B(ns=1); MFMA (0,1) ===============
#pragma unroll
        for (int j = 0; j < 2; j++) {
            bfr[1][j][0] = *(const bf16x8*)(bb + 4096 + j * 2048 + cs0);
            bfr[1][j][1] = *(const bf16x8*)(bb + 4096 + j * 2048 + cs1);
        }
        asm volatile("" ::: "memory");
        __builtin_amdgcn_s_barrier();
        asm volatile("s_waitcnt lgkmcnt(0)" ::: "memory");
        __builtin_amdgcn_sched_barrier(0);
        __builtin_amdgcn_s_setprio(1);
#pragma unroll
        for (int i = 0; i < 4; i++)
#pragma unroll
            for (int j = 0; j < 2; j++) {
                acc[0][1][i][j] = MFMA16(af[i][0], bfr[1][j][0], acc[0][1][i][j]);
                acc[0][1][i][j] = MFMA16(af[i][1], bfr[1][j][1], acc[0][1][i][j]);
            }
        __builtin_amdgcn_s_setprio(0);
        asm volatile("" ::: "memory");
        __builtin_amdgcn_s_barrier();
        asm volatile("" ::: "memory");

        // ====== phase 2: read A(ms=1); stage B(kt+2); MFMA (1,1) ===========
        // B regions' last reads were phase 1 (barrier-separated) -> safe.
#pragma unroll
        for (int i = 0; i < 4; i++) {
            af[i][0] = *(const bf16x8*)(ab + 8192 + i * 2048 + cs0);
            af[i][1] = *(const bf16x8*)(ab + 8192 + i * 2048 + cs1);
        }
        if (st) {
            stage(gB0, &sB[buf][0][0], 0, kt + 2);
            stage(gB0, &sB[buf][0][0], 1, kt + 2);
        }
        asm volatile("" ::: "memory");
        __builtin_amdgcn_s_barrier();
        asm volatile("s_waitcnt lgkmcnt(0)" ::: "memory");
        __builtin_amdgcn_sched_barrier(0);
        __builtin_amdgcn_s_setprio(1);
#pragma unroll
        for (int i = 0; i < 4; i++)
#pragma unroll
            for (int j = 0; j < 2; j++) {
                acc[1][1][i][j] = MFMA16(af[i][0], bfr[1][j][0], acc[1][1][i][j]);
                acc[1][1][i][j] = MFMA16(af[i][1], bfr[1][j][1], acc[1][1][i][j]);
            }
        __builtin_amdgcn_s_setprio(0);
        asm volatile("" ::: "memory");
        __builtin_amdgcn_s_barrier();
        asm volatile("" ::: "memory");

        // ====== phase 3: stage A(kt+2); MFMA (1,0); counted vmcnt ==========
        // A regions' last reads were phase 2 (barrier-separated) -> safe.
        if (st) {
            stage(gA0, &sA[buf][0][0], 0, kt + 2);
            stage(gA0, &sA[buf][0][0], 1, kt + 2);
        }
        asm volatile("" ::: "memory");
        __builtin_amdgcn_s_barrier();
        __builtin_amdgcn_sched_barrier(0);
        __builtin_amdgcn_s_setprio(1);
#pragma unroll
        for (int i = 0; i < 4; i++)
#pragma unroll
            for (int j = 0; j < 2; j++) {
                acc[1][0][i][j] = MFMA16(af[i][0], bfr[0][j][0], acc[1][0][i][j]);
                acc[1][0][i][j] = MFMA16(af[i][1], bfr[0][j][1], acc[1][0][i][j]);
            }
        __builtin_amdgcn_s_setprio(0);
        // drain everything except this iteration's 8 issues (kt+1 data lands)
        if (kt < NKT - 2) asm volatile("s_waitcnt vmcnt(8)" ::: "memory");
        else              asm volatile("s_waitcnt vmcnt(0)" ::: "memory");
        asm volatile("" ::: "memory");
        __builtin_amdgcn_s_barrier();
        asm volatile("" ::: "memory");
    }

    // ---- epilogue: C/D layout col=lane&15, row=(lane>>4)*4+reg ----
    if constexpr (OUT_BF16) {
        bf16* C = (bf16*)Cout;
#pragma unroll
        for (int ms = 0; ms < 2; ms++)
#pragma unroll
            for (int ns = 0; ns < 2; ns++)
#pragma unroll
                for (int i = 0; i < 4; i++)
#pragma unroll
                    for (int j = 0; j < 2; j++)
#pragma unroll
                        for (int r = 0; r < 4; r++) {
                            const int row = bm + wm * 128 + ms * 64 + i * 16 + fq * 4 + r;
                            const int col = bn + wn * 64 + ns * 32 + j * 16 + fr;
                            C[(size_t)row * N + col] = (bf16)acc[ms][ns][i][j][r];
                        }
    } else {
        float* C = (float*)Cout;
#pragma unroll
        for (int ms = 0; ms < 2; ms++)
#pragma unroll
            for (int ns = 0; ns < 2; ns++)
#pragma unroll
                for (int i = 0; i < 4; i++)
#pragma unroll
                    for (int j = 0; j < 2; j++)
#pragma unroll
                        for (int r = 0; r < 4; r++) {
                            const int row = bm + wm * 128 + ms * 64 + i * 16 + fq * 4 + r;
                            const int col = bn + wn * 64 + ns * 32 + j * 16 + fr;
                            C[(size_t)row * N + col] = acc[ms][ns][i][j][r] + bias[col];
                        }
    }
}

// ---------------------------------------------------------------------------
// MFMA attention: one 64-thread wave per (n, head). T=32, D=64. (unchanged)
// ---------------------------------------------------------------------------
__global__ __launch_bounds__(64)
void taa_attn_mfma(const bf16* __restrict__ qkv, bf16* __restrict__ o) {
    __shared__ __align__(16) bf16 sQ[32 * 72];   // stride 72: +8 pad -> 2-way banks
    __shared__ __align__(16) bf16 sK[32 * 72];
    __shared__ __align__(16) bf16 sVt[64 * 40];  // V^T [d][t], stride 40
    __shared__ __align__(16) bf16 sP[32 * 40];   // P   [tq][tk], stride 40

    const int lane = threadIdx.x;
    const int bid  = blockIdx.x;        // n*16 + head
    const int head = bid & 15;
    const int n    = bid >> 4;          // (b*18 + h)*32 + w
    const int w_sp = n & 31;
    const int h_sp = (n >> 5) % 18;
    const int b    = n / (18 * 32);
    const int m0   = b * 18432 + h_sp * 32 + w_sp;   // row for t=0

    // ---- load Q,K (RoPE) and V (transposed) into LDS ----
    {
        const int tl = lane >> 3;          // 0..7
        const int dl = (lane & 7) * 8;     // 0..56
#pragma unroll
        for (int it = 0; it < 4; ++it) {
            const int t = it * 8 + tl;
            const size_t rb = (size_t)(m0 + t * T_STRIDE) * E3 + head * 64 + dl;
            bf16x8 q8 = *(const bf16x8*)(qkv + rb);
            bf16x8 k8 = *(const bf16x8*)(qkv + rb + 1024);
            bf16x8 v8 = *(const bf16x8*)(qkv + rb + 2048);
            float qf[8], kf[8];
#pragma unroll
            for (int j = 0; j < 8; j++) { qf[j] = (float)q8[j]; kf[j] = (float)k8[j]; }
            if (dl < 32) {
#pragma unroll
                for (int p = 0; p < 4; p++) {
                    const int fi = dl / 2 + p;                   // pair 0..15
                    float freq = exp2f(-(float)fi * 0.830482024f); // 10000^(-fi/16)
                    float ang  = (float)t * freq;
                    float s, c;
                    sincosf(ang, &s, &c);
                    float a = qf[2 * p], bb = qf[2 * p + 1];
                    qf[2 * p]     = a * c - bb * s;
                    qf[2 * p + 1] = bb * c + a * s;
                    a = kf[2 * p]; bb = kf[2 * p + 1];
                    kf[2 * p]     = a * c - bb * s;
                    kf[2 * p + 1] = bb * c + a * s;
                }
            }
            bf16x8 qo, ko;
#pragma unroll
            for (int j = 0; j < 8; j++) { qo[j] = (bf16)qf[j]; ko[j] = (bf16)kf[j]; }
            *(bf16x8*)&sQ[t * 72 + dl] = qo;
            *(bf16x8*)&sK[t * 72 + dl] = ko;
#pragma unroll
            for (int j = 0; j < 8; j++) sVt[(dl + j) * 40 + t] = v8[j];
        }
    }
    __syncthreads();

    const int fr = lane & 15;
    const int fq = lane >> 4;            // 0..3

    // ---- S = Q K^T, 2x2 tiles, K=64 ----
    f32x4 S[2][2];
#pragma unroll
    for (int mt = 0; mt < 2; mt++)
#pragma unroll
        for (int nt = 0; nt < 2; nt++) S[mt][nt] = (f32x4){0.f, 0.f, 0.f, 0.f};

    bf16x8 kb0[2], kb1[2];
#pragma unroll
    for (int nt = 0; nt < 2; nt++) {
        kb0[nt] = *(const bf16x8*)&sK[(nt * 16 + fr) * 72 + fq * 8];
        kb1[nt] = *(const bf16x8*)&sK[(nt * 16 + fr) * 72 + 32 + fq * 8];
    }
#pragma unroll
    for (int mt = 0; mt < 2; mt++) {
        bf16x8 a0 = *(const bf16x8*)&sQ[(mt * 16 + fr) * 72 + fq * 8];
        bf16x8 a1 = *(const bf16x8*)&sQ[(mt * 16 + fr) * 72 + 32 + fq * 8];
#pragma unroll
        for (int nt = 0; nt < 2; nt++) {
            S[mt][nt] = __builtin_amdgcn_mfma_f32_16x16x32_bf16(a0, kb0[nt], S[mt][nt], 0, 0, 0);
            S[mt][nt] = __builtin_amdgcn_mfma_f32_16x16x32_bf16(a1, kb1[nt], S[mt][nt], 0, 0, 0);
        }
    }

    // ---- causal softmax in registers ----
    float P[2][2][4];
#pragma unroll
    for (int mt = 0; mt < 2; mt++) {
#pragma unroll
        for (int r = 0; r < 4; r++) {
            const int row = mt * 16 + fq * 4 + r;
            float s0 = S[mt][0][r] * 0.125f;
            float s1 = S[mt][1][r] * 0.125f;
            if (fr > row)      s0 = -1e30f;
            if (16 + fr > row) s1 = -1e30f;
            float mx = fmaxf(s0, s1);
#pragma unroll
            for (int mk = 1; mk <= 8; mk <<= 1) mx = fmaxf(mx, __shfl_xor(mx, mk, 64));
            float e0 = __expf(s0 - mx);
            float e1 = __expf(s1 - mx);
            float sm = e0 + e1;
#pragma unroll
            for (int mk = 1; mk <= 8; mk <<= 1) sm += __shfl_xor(sm, mk, 64);
            float inv = 1.0f / sm;
            P[mt][0][r] = e0 * inv;
            P[mt][1][r] = e1 * inv;
        }
    }

    // ---- P -> LDS (C-layout scatter), read back in A-layout ----
#pragma unroll
    for (int mt = 0; mt < 2; mt++)
#pragma unroll
        for (int nt = 0; nt < 2; nt++)
#pragma unroll
            for (int r = 0; r < 4; r++)
                sP[(mt * 16 + fq * 4 + r) * 40 + nt * 16 + fr] = (bf16)P[mt][nt][r];
    __syncthreads();

    // ---- O = P V, 2x4 tiles, K=32 ----
    f32x4 O[2][4];
#pragma unroll
    for (int mt = 0; mt < 2; mt++)
#pragma unroll
        for (int dt = 0; dt < 4; dt++) O[mt][dt] = (f32x4){0.f, 0.f, 0.f, 0.f};
#pragma unroll
    for (int mt = 0; mt < 2; mt++) {
        bf16x8 a = *(const bf16x8*)&sP[(mt * 16 + fr) * 40 + fq * 8];
#pragma unroll
        for (int dt = 0; dt < 4; dt++) {
            bf16x8 bv = *(const bf16x8*)&sVt[(dt * 16 + fr) * 40 + fq * 8];
            O[mt][dt] = __builtin_amdgcn_mfma_f32_16x16x32_bf16(a, bv, O[mt][dt], 0, 0, 0);
        }
    }

    // ---- write O: row t = mt*16+fq*4+r, col d = dt*16+fr ----
#pragma unroll
    for (int mt = 0; mt < 2; mt++)
#pragma unroll
        for (int dt = 0; dt < 4; dt++)
#pragma unroll
            for (int r = 0; r < 4; r++) {
                const int t = mt * 16 + fq * 4 + r;
                const int d = dt * 16 + fr;
                o[(size_t)(m0 + t * T_STRIDE) * DIM + head * 64 + d] = (bf16)O[mt][dt][r];
            }
}

// ---------------------------------------------------------------------------
extern "C" void kernel_launch(void* const* d_in, const int* in_sizes, int n_in,
                              void* d_out, int out_size, void* d_ws, size_t ws_size,
                              hipStream_t stream) {
    const float* x     = (const float*)d_in[0];
    const float* w_qkv = (const float*)d_in[1];
    const float* w_out = (const float*)d_in[2];
    const float* b_out = (const float*)d_in[3];

    char* ws = (char*)d_ws;
    // workspace layout (bytes)
    bf16* x_b    = (bf16*)(ws + 0);            //  75,497,472  x as bf16
    bf16* wqkv_b = (bf16*)(ws + 75497472);     //   6,291,456
    bf16* wout_b = (bf16*)(ws + 81788928);     //   2,097,152
    bf16* qkv_b  = (bf16*)(ws + 83886080);     // 226,492,416  qkv [M,3072] bf16
    bf16* o_b    = (bf16*)(ws + 310378496);    //  75,497,472  o   [M,1024] bf16
                                               // total 385,875,968

    // convert inputs to bf16
    taa_cvt_bf16<<<(M_TOT * DIM / 4 + 255) / 256, 256, 0, stream>>>(x, x_b, M_TOT * DIM / 4);
    taa_cvt_bf16<<<(E3 * DIM / 4 + 255) / 256, 256, 0, stream>>>(w_qkv, wqkv_b, E3 * DIM / 4);
    taa_cvt_bf16<<<(DIM * DIM / 4 + 255) / 256, 256, 0, stream>>>(w_out, wout_b, DIM * DIM / 4);

    // QKV projection: [36864,3072] = x_b[36864,1024] * wqkv_b[3072,1024]^T
    taa_gemm256<true><<<dim3((M_TOT / 256) * (E3 / 256)), 512, 0, stream>>>(
        x_b, wqkv_b, (void*)qkv_b, nullptr, E3);

    // MFMA attention: one wave per (n, head)
    taa_attn_mfma<<<1152 * 16, 64, 0, stream>>>(qkv_b, o_b);

    // output projection: d_out[36864,1024] = o_b * wout_b^T + b_out
    taa_gemm256<false><<<dim3((M_TOT / 256) * (DIM / 256)), 512, 0, stream>>>(
        o_b, wout_b, d_out, b_out, DIM);
}

// Round 4
// 695.719 us; speedup vs baseline: 1.0887x; 1.0338x over previous
//
#include <hip/hip_runtime.h>
#include <cstdint>
#include <cstddef>

typedef __bf16 bf16;
typedef __attribute__((ext_vector_type(8))) bf16  bf16x8;
typedef __attribute__((ext_vector_type(4))) bf16  bf16x4;
typedef __attribute__((ext_vector_type(4))) float f32x4;

// Problem constants
#define B_SZ   2
#define T_SZ   32
#define H_SZ   18
#define W_SZ   32
#define DIM    1024
#define NHEAD  16
#define HDIM   64
#define E3     3072                  // 3*NHEAD*HDIM
#define M_TOT  36864                 // B*T*H*W
#define T_STRIDE 576                 // H_SZ*W_SZ rows per t step
#define GK     1024                  // K of both GEMMs (compile-time)
#define NKT    16                    // GK / 64

// ---------------------------------------------------------------------------
// fp32 -> bf16 conversion (vectorized x4)
// ---------------------------------------------------------------------------
__global__ void taa_cvt_bf16(const float* __restrict__ s, bf16* __restrict__ d, int n4) {
    int i = blockIdx.x * 256 + threadIdx.x;
    if (i >= n4) return;
    float4 v = ((const float4*)s)[i];
    bf16x4 o;
    o.x = (bf16)v.x; o.y = (bf16)v.y; o.z = (bf16)v.z; o.w = (bf16)v.w;
    ((bf16x4*)d)[i] = o;
}

// ---------------------------------------------------------------------------
// async global->LDS 16B (wave-uniform base + lane*16 semantics)
// ---------------------------------------------------------------------------
__device__ __forceinline__ void async_copy_16(const bf16* g, bf16* l) {
    __builtin_amdgcn_global_load_lds((__attribute__((address_space(1))) void*)g,
                                     (__attribute__((address_space(3))) void*)l,
                                     16, 0, 0);
}

#define MFMA16(a, b, c) __builtin_amdgcn_mfma_f32_16x16x32_bf16((a), (b), (c), 0, 0, 0)

// ---------------------------------------------------------------------------
// C[M,N] = A[M,K] * B[N,K]^T, bf16 in, fp32 accumulate. 256x256 tile, BK=64,
// 512 threads = 8 waves (2M x 4N), each wave 128x64 output.
//
// 2-sync-point K-tile (revised from the 8-barrier phase-locked version whose
// measured MfmaUtil was 36%: reads and MFMA were serialized by barrier pairs):
//   [entry: kt data landed, waves synced]
//   issue ALL 24 ds_read_b128 (af, bf0, bf1, ag)   -- plain loads; compiler
//   MFMA quadrants (0,0),(0,1)                        emits counted lgkmcnt,
//                                                     reads stream under MFMA
//   lgkmcnt(0); s_barrier       -- every wave's reads retired before staging
//   stage B(kt+2), A(kt+2)      -- depth-2 prefetch into same-parity buffer
//   MFMA quadrants (1,1),(1,0)  -- pure-register
//   vmcnt(8); s_barrier         -- kt+1 landed; kt+2's 8 issues stay in flight
// Never vmcnt(0) in steady state (T4). setprio around MFMA clusters (T5).
//
// LDS: [2 dbuf][2 half][128][64] bf16 for A and B = 128 KiB total.
// Bank-conflict fix (T2): 16B-chunk XOR swizzle chunk ^= (row&7), applied on
// the pre-swizzled GLOBAL source of global_load_lds (dest stays linear) and
// identically on the ds_read side (row%8 == fr%8 for every fragment row).
// XCD-aware bijective blockIdx swizzle (grid % 8 == 0 for both GEMMs).
// ---------------------------------------------------------------------------
template<bool OUT_BF16>
__global__ __launch_bounds__(512, 2)
void taa_gemm256(const bf16* __restrict__ A, const bf16* __restrict__ Bm,
                 void* __restrict__ Cout, const float* __restrict__ bias, int N) {
    __shared__ __align__(16) bf16 sA[2][2][8192];   // [buf][half][128*64]
    __shared__ __align__(16) bf16 sB[2][2][8192];

    const int tid  = threadIdx.x;
    const int lane = tid & 63;
    const int wv   = tid >> 6;          // 0..7
    const int wm   = wv >> 2;           // 0..1 : wave rows  wm*128
    const int wn   = wv & 3;            // 0..3 : wave cols  wn*64
    const int fr   = lane & 15;
    const int fq   = lane >> 4;

    // XCD-aware bijective swizzle (nwg % 8 == 0 guaranteed by launch)
    const int ntn = N >> 8;
    const int nwg = gridDim.x;
    const int bid = blockIdx.x;
    const int swz = (bid & 7) * (nwg >> 3) + (bid >> 3);
    const int bm  = (swz / ntn) << 8;
    const int bn  = (swz % ntn) << 8;

    // staging: per issue, thread covers LDS element range [issue*4096 + tid*8, +8)
    // of a 16KB half-buffer (linear dest). Logical row = issue*64 + tid>>3,
    // source col chunk pre-swizzled: (tid&7) ^ (row&7).
    const int srow = tid >> 3;                          // 0..63
    const int scol = ((tid & 7) ^ (srow & 7)) << 3;     // element col in [0,64)
    const bf16* gA0 = A  + (size_t)(bm + srow) * GK + scol;
    const bf16* gB0 = Bm + (size_t)(bn + srow) * GK + scol;

    // per-lane swizzled k-chunk byte offsets for fragment ds_reads
    const int swx = (fr & 7) << 4;
    const int cs0 = (fq * 16) ^ swx;          // k-step 0
    const int cs1 = (64 + fq * 16) ^ swx;     // k-step 1

    f32x4 acc[2][2][4][2];                    // [ms][ns][i][j]
#pragma unroll
    for (int ms = 0; ms < 2; ms++)
#pragma unroll
        for (int ns = 0; ns < 2; ns++)
#pragma unroll
            for (int i = 0; i < 4; i++)
#pragma unroll
                for (int j = 0; j < 2; j++)
                    acc[ms][ns][i][j] = (f32x4){0.f, 0.f, 0.f, 0.f};

    // one stage() = one 16KB half-tile = 2 global_load_lds per wave
    auto stage = [&](const bf16* g0, bf16* lbase, int h, int kt) {
        const bf16* g = g0 + (size_t)(h * 128) * GK + kt * 64;
        async_copy_16(g,                    lbase + h * 8192 + tid * 8);
        async_copy_16(g + (size_t)64 * GK,  lbase + h * 8192 + 4096 + tid * 8);
    };

    // ---- prologue: stage kt=0 -> buf0, kt=1 -> buf1 (16 issues/wave-lane) ----
    stage(gB0, &sB[0][0][0], 0, 0); stage(gB0, &sB[0][0][0], 1, 0);
    stage(gA0, &sA[0][0][0], 0, 0); stage(gA0, &sA[0][0][0], 1, 0);
    stage(gB0, &sB[1][0][0], 0, 1); stage(gB0, &sB[1][0][0], 1, 1);
    stage(gA0, &sA[1][0][0], 0, 1); stage(gA0, &sA[1][0][0], 1, 1);
    asm volatile("s_waitcnt vmcnt(8)" ::: "memory");   // kt=0 fully landed
    __builtin_amdgcn_s_barrier();
    asm volatile("" ::: "memory");

#pragma unroll 2
    for (int kt = 0; kt < NKT; ++kt) {
        const int buf = kt & 1;
        const char* ab = (const char*)&sA[buf][wm][0] + fr * 128;
        const char* bb = (const char*)&sB[buf][wn >> 1][0] + ((wn & 1) * 64 + fr) * 128;
        const bool st = (kt + 2 < NKT);

        // ===== region 1: issue ALL fragment reads; MFMA (0,0) and (0,1) =====
        bf16x8 af[4][2];    // A half ms=0
        bf16x8 ag[4][2];    // A half ms=1
        bf16x8 bf0[2][2];   // B ns=0
        bf16x8 bf1[2][2];   // B ns=1

        af[0][0] = *(const bf16x8*)(ab + cs0);
        af[0][1] = *(const bf16x8*)(ab + cs1);
#pragma unroll
        for (int j = 0; j < 2; j++) {
            bf0[j][0] = *(const bf16x8*)(bb + j * 2048 + cs0);
            bf0[j][1] = *(const bf16x8*)(bb + j * 2048 + cs1);
        }
#pragma unroll
        for (int i = 1; i < 4; i++) {
            af[i][0] = *(const bf16x8*)(ab + i * 2048 + cs0);
            af[i][1] = *(const bf16x8*)(ab + i * 2048 + cs1);
        }
#pragma unroll
        for (int j = 0; j < 2; j++) {
            bf1[j][0] = *(const bf16x8*)(bb + 4096 + j * 2048 + cs0);
            bf1[j][1] = *(const bf16x8*)(bb + 4096 + j * 2048 + cs1);
        }
#pragma unroll
        for (int i = 0; i < 4; i++) {
            ag[i][0] = *(const bf16x8*)(ab + 8192 + i * 2048 + cs0);
            ag[i][1] = *(const bf16x8*)(ab + 8192 + i * 2048 + cs1);
        }

        __builtin_amdgcn_s_setprio(1);
#pragma unroll
        for (int i = 0; i < 4; i++)
#pragma unroll
            for (int j = 0; j < 2; j++) {
                acc[0][0][i][j] = MFMA16(af[i][0], bf0[j][0], acc[0][0][i][j]);
                acc[0][0][i][j] = MFMA16(af[i][1], bf0[j][1], acc[0][0][i][j]);
            }
#pragma unroll
        for (int i = 0; i < 4; i++)
#pragma unroll
            for (int j = 0; j < 2; j++) {
                acc[0][1][i][j] = MFMA16(af[i][0], bf1[j][0], acc[0][1][i][j]);
                acc[0][1][i][j] = MFMA16(af[i][1], bf1[j][1], acc[0][1][i][j]);
            }
        __builtin_amdgcn_s_setprio(0);

        // every wave's 24 reads retired (issued ~600cy ago -> near-free wait);
        // required before staging DMA may overwrite these regions.
        asm volatile("s_waitcnt lgkmcnt(0)" ::: "memory");
        __builtin_amdgcn_s_barrier();
        asm volatile("" ::: "memory");

        // ===== region 2: stage kt+2; MFMA (1,1) and (1,0); counted vmcnt ====
        if (st) {
            stage(gB0, &sB[buf][0][0], 0, kt + 2);
            stage(gB0, &sB[buf][0][0], 1, kt + 2);
            stage(gA0, &sA[buf][0][0], 0, kt + 2);
            stage(gA0, &sA[buf][0][0], 1, kt + 2);
        }
        __builtin_amdgcn_s_setprio(1);
#pragma unroll
        for (int i = 0; i < 4; i++)
#pragma unroll
            for (int j = 0; j < 2; j++) {
                acc[1][1][i][j] = MFMA16(ag[i][0], bf1[j][0], acc[1][1][i][j]);
                acc[1][1][i][j] = MFMA16(ag[i][1], bf1[j][1], acc[1][1][i][j]);
            }
#pragma unroll
        for (int i = 0; i < 4; i++)
#pragma unroll
            for (int j = 0; j < 2; j++) {
                acc[1][0][i][j] = MFMA16(ag[i][0], bf0[j][0], acc[1][0][i][j]);
                acc[1][0][i][j] = MFMA16(ag[i][1], bf0[j][1], acc[1][0][i][j]);
            }
        __builtin_amdgcn_s_setprio(0);
        // drain kt+1's staging (oldest 8); keep kt+2's 8 issues in flight
        if (kt < NKT - 2) asm volatile("s_waitcnt vmcnt(8)" ::: "memory");
        else              asm volatile("s_waitcnt vmcnt(0)" ::: "memory");
        __builtin_amdgcn_s_barrier();
        asm volatile("" ::: "memory");
    }

    // ---- epilogue: C/D layout col=lane&15, row=(lane>>4)*4+reg ----
    if constexpr (OUT_BF16) {
        bf16* C = (bf16*)Cout;
#pragma unroll
        for (int ms = 0; ms < 2; ms++)
#pragma unroll
            for (int ns = 0; ns < 2; ns++)
#pragma unroll
                for (int i = 0; i < 4; i++)
#pragma unroll
                    for (int j = 0; j < 2; j++)
#pragma unroll
                        for (int r = 0; r < 4; r++) {
                            const int row = bm + wm * 128 + ms * 64 + i * 16 + fq * 4 + r;
                            const int col = bn + wn * 64 + ns * 32 + j * 16 + fr;
                            C[(size_t)row * N + col] = (bf16)acc[ms][ns][i][j][r];
                        }
    } else {
        float* C = (float*)Cout;
#pragma unroll
        for (int ms = 0; ms < 2; ms++)
#pragma unroll
            for (int ns = 0; ns < 2; ns++)
#pragma unroll
                for (int i = 0; i < 4; i++)
#pragma unroll
                    for (int j = 0; j < 2; j++)
#pragma unroll
                        for (int r = 0; r < 4; r++) {
                            const int row = bm + wm * 128 + ms * 64 + i * 16 + fq * 4 + r;
                            const int col = bn + wn * 64 + ns * 32 + j * 16 + fr;
                            C[(size_t)row * N + col] = acc[ms][ns][i][j][r] + bias[col];
                        }
    }
}

// ---------------------------------------------------------------------------
// MFMA attention: one 64-thread wave per (n, head). T=32, D=64.
// (unchanged except sincosf -> __sincosf fast intrinsic)
// ---------------------------------------------------------------------------
__global__ __launch_bounds__(64)
void taa_attn_mfma(const bf16* __restrict__ qkv, bf16* __restrict__ o) {
    __shared__ __align__(16) bf16 sQ[32 * 72];   // stride 72: +8 pad -> 2-way banks
    __shared__ __align__(16) bf16 sK[32 * 72];
    __shared__ __align__(16) bf16 sVt[64 * 40];  // V^T [d][t], stride 40
    __shared__ __align__(16) bf16 sP[32 * 40];   // P   [tq][tk], stride 40

    const int lane = threadIdx.x;
    const int bid  = blockIdx.x;        // n*16 + head
    const int head = bid & 15;
    const int n    = bid >> 4;          // (b*18 + h)*32 + w
    const int w_sp = n & 31;
    const int h_sp = (n >> 5) % 18;
    const int b    = n / (18 * 32);
    const int m0   = b * 18432 + h_sp * 32 + w_sp;   // row for t=0

    // ---- load Q,K (RoPE) and V (transposed) into LDS ----
    {
        const int tl = lane >> 3;          // 0..7
        const int dl = (lane & 7) * 8;     // 0..56
#pragma unroll
        for (int it = 0; it < 4; ++it) {
            const int t = it * 8 + tl;
            const size_t rb = (size_t)(m0 + t * T_STRIDE) * E3 + head * 64 + dl;
            bf16x8 q8 = *(const bf16x8*)(qkv + rb);
            bf16x8 k8 = *(const bf16x8*)(qkv + rb + 1024);
            bf16x8 v8 = *(const bf16x8*)(qkv + rb + 2048);
            float qf[8], kf[8];
#pragma unroll
            for (int j = 0; j < 8; j++) { qf[j] = (float)q8[j]; kf[j] = (float)k8[j]; }
            if (dl < 32) {
#pragma unroll
                for (int p = 0; p < 4; p++) {
                    const int fi = dl / 2 + p;                   // pair 0..15
                    float freq = exp2f(-(float)fi * 0.830482024f); // 10000^(-fi/16)
                    float ang  = (float)t * freq;
                    float s, c;
                    __sincosf(ang, &s, &c);
                    float a = qf[2 * p], bb = qf[2 * p + 1];
                    qf[2 * p]     = a * c - bb * s;
                    qf[2 * p + 1] = bb * c + a * s;
                    a = kf[2 * p]; bb = kf[2 * p + 1];
                    kf[2 * p]     = a * c - bb * s;
                    kf[2 * p + 1] = bb * c + a * s;
                }
            }
            bf16x8 qo, ko;
#pragma unroll
            for (int j = 0; j < 8; j++) { qo[j] = (bf16)qf[j]; ko[j] = (bf16)kf[j]; }
            *(bf16x8*)&sQ[t * 72 + dl] = qo;
            *(bf16x8*)&sK[t * 72 + dl] = ko;
#pragma unroll
            for (int j = 0; j < 8; j++) sVt[(dl + j) * 40 + t] = v8[j];
        }
    }
    __syncthreads();

    const int fr = lane & 15;
    const int fq = lane >> 4;            // 0..3

    // ---- S = Q K^T, 2x2 tiles, K=64 ----
    f32x4 S[2][2];
#pragma unroll
    for (int mt = 0; mt < 2; mt++)
#pragma unroll
        for (int nt = 0; nt < 2; nt++) S[mt][nt] = (f32x4){0.f, 0.f, 0.f, 0.f};

    bf16x8 kb0[2], kb1[2];
#pragma unroll
    for (int nt = 0; nt < 2; nt++) {
        kb0[nt] = *(const bf16x8*)&sK[(nt * 16 + fr) * 72 + fq * 8];
        kb1[nt] = *(const bf16x8*)&sK[(nt * 16 + fr) * 72 + 32 + fq * 8];
    }
#pragma unroll
    for (int mt = 0; mt < 2; mt++) {
        bf16x8 a0 = *(const bf16x8*)&sQ[(mt * 16 + fr) * 72 + fq * 8];
        bf16x8 a1 = *(const bf16x8*)&sQ[(mt * 16 + fr) * 72 + 32 + fq * 8];
#pragma unroll
        for (int nt = 0; nt < 2; nt++) {
            S[mt][nt] = __builtin_amdgcn_mfma_f32_16x16x32_bf16(a0, kb0[nt], S[mt][nt], 0, 0, 0);
            S[mt][nt] = __builtin_amdgcn_mfma_f32_16x16x32_bf16(a1, kb1[nt], S[mt][nt], 0, 0, 0);
        }
    }

    // ---- causal softmax in registers ----
    float P[2][2][4];
#pragma unroll
    for (int mt = 0; mt < 2; mt++) {
#pragma unroll
        for (int r = 0; r < 4; r++) {
            const int row = mt * 16 + fq * 4 + r;
            float s0 = S[mt][0][r] * 0.125f;
            float s1 = S[mt][1][r] * 0.125f;
            if (fr > row)      s0 = -1e30f;
            if (16 + fr > row) s1 = -1e30f;
            float mx = fmaxf(s0, s1);
#pragma unroll
            for (int mk = 1; mk <= 8; mk <<= 1) mx = fmaxf(mx, __shfl_xor(mx, mk, 64));
            float e0 = __expf(s0 - mx);
            float e1 = __expf(s1 - mx);
            float sm = e0 + e1;
#pragma unroll
            for (int mk = 1; mk <= 8; mk <<= 1) sm += __shfl_xor(sm, mk, 64);
            float inv = 1.0f / sm;
            P[mt][0][r] = e0 * inv;
            P[mt][1][r] = e1 * inv;
        }
    }

    // ---- P -> LDS (C-layout scatter), read back in A-layout ----
#pragma unroll
    for (int mt = 0; mt < 2; mt++)
#pragma unroll
        for (int nt = 0; nt < 2; nt++)
#pragma unroll
            for (int r = 0; r < 4; r++)
                sP[(mt * 16 + fq * 4 + r) * 40 + nt * 16 + fr] = (bf16)P[mt][nt][r];
    __syncthreads();

    // ---- O = P V, 2x4 tiles, K=32 ----
    f32x4 O[2][4];
#pragma unroll
    for (int mt = 0; mt < 2; mt++)
#pragma unroll
        for (int dt = 0; dt < 4; dt++) O[mt][dt] = (f32x4){0.f, 0.f, 0.f, 0.f};
#pragma unroll
    for (int mt = 0; mt < 2; mt++) {
        bf16x8 a = *(const bf16x8*)&sP[(mt * 16 + fr) * 40 + fq * 8];
#pragma unroll
        for (int dt = 0; dt < 4; dt++) {
            bf16x8 bv = *(const bf16x8*)&sVt[(dt * 16 + fr) * 40 + fq * 8];
            O[mt][dt] = __builtin_amdgcn_mfma_f32_16x16x32_bf16(a, bv, O[mt][dt], 0, 0, 0);
        }
    }

    // ---- write O: row t = mt*16+fq*4+r, col d = dt*16+fr ----
#pragma unroll
    for (int mt = 0; mt < 2; mt++)
#pragma unroll
        for (int dt = 0; dt < 4; dt++)
#pragma unroll
            for (int r = 0; r < 4; r++) {
                const int t = mt * 16 + fq * 4 + r;
                const int d = dt * 16 + fr;
                o[(size_t)(m0 + t * T_STRIDE) * DIM + head * 64 + d] = (bf16)O[mt][dt][r];
            }
}

// ---------------------------------------------------------------------------
extern "C" void kernel_launch(void* const* d_in, const int* in_sizes, int n_in,
                              void* d_out, int out_size, void* d_ws, size_t ws_size,
                              hipStream_t stream) {
    const float* x     = (const float*)d_in[0];
    const float* w_qkv = (const float*)d_in[1];
    const float* w_out = (const float*)d_in[2];
    const float* b_out = (const float*)d_in[3];

    char* ws = (char*)d_ws;
    // workspace layout (bytes)
    bf16* x_b    = (bf16*)(ws + 0);            //  75,497,472  x as bf16
    bf16* wqkv_b = (bf16*)(ws + 75497472);     //   6,291,456
    bf16* wout_b = (bf16*)(ws + 81788928);     //   2,097,152
    bf16* qkv_b  = (bf16*)(ws + 83886080);     // 226,492,416  qkv [M,3072] bf16
    bf16* o_b    = (bf16*)(ws + 310378496);    //  75,497,472  o   [M,1024] bf16
                                               // total 385,875,968

    // convert inputs to bf16
    taa_cvt_bf16<<<(M_TOT * DIM / 4 + 255) / 256, 256, 0, stream>>>(x, x_b, M_TOT * DIM / 4);
    taa_cvt_bf16<<<(E3 * DIM / 4 + 255) / 256, 256, 0, stream>>>(w_qkv, wqkv_b, E3 * DIM / 4);
    taa_cvt_bf16<<<(DIM * DIM / 4 + 255) / 256, 256, 0, stream>>>(w_out, wout_b, DIM * DIM / 4);

    // QKV projection: [36864,3072] = x_b[36864,1024] * wqkv_b[3072,1024]^T
    taa_gemm256<true><<<dim3((M_TOT / 256) * (E3 / 256)), 512, 0, stream>>>(
        x_b, wqkv_b, (void*)qkv_b, nullptr, E3);

    // MFMA attention: one wave per (n, head)
    taa_attn_mfma<<<1152 * 16, 64, 0, stream>>>(qkv_b, o_b);

    // output projection: d_out[36864,1024] = o_b * wout_b^T + b_out
    taa_gemm256<false><<<dim3((M_TOT / 256) * (DIM / 256)), 512, 0, stream>>>(
        o_b, wout_b, d_out, b_out, DIM);
}